// Round 1
// baseline (362.594 us; speedup 1.0000x reference)
//
#include <hip/hip_runtime.h>

#define D 128
#define TN 32

// ---- 1) count in-degree over targets (col = edge_index[1]) ----
__global__ void count_kernel(const int* __restrict__ ei, int E, int* __restrict__ deg) {
    int e = blockIdx.x * blockDim.x + threadIdx.x;
    if (e < E) atomicAdd(&deg[ei[E + e]], 1);
}

// ---- 2) exclusive scan of degrees -> CSR offsets + cursor copy + dinv ----
__global__ __launch_bounds__(1024) void scan_kernel(const int* __restrict__ deg, int n,
                                                    int* __restrict__ offs, int* __restrict__ cursor,
                                                    float* __restrict__ dinv) {
    __shared__ int buf[2][1024];
    __shared__ int carry_s;
    int tid = threadIdx.x;
    if (tid == 0) carry_s = 0;
    __syncthreads();
    for (int base = 0; base < n; base += 1024) {
        int i = base + tid;
        int v = (i < n) ? deg[i] : 0;
        buf[0][tid] = v;
        __syncthreads();
        int src = 0;
        for (int off = 1; off < 1024; off <<= 1) {
            int val = buf[src][tid];
            if (tid >= off) val += buf[src][tid - off];
            buf[1 - src][tid] = val;
            src ^= 1;
            __syncthreads();
        }
        int incl = buf[src][tid];
        int carry = carry_s;
        if (i < n) {
            int excl = carry + incl - v;
            offs[i] = excl;
            cursor[i] = excl;
            dinv[i] = rsqrtf((float)(v + 1));  // +1 self-loop; deg>=1 always
        }
        __syncthreads();
        if (tid == 1023) carry_s = carry + incl;
        __syncthreads();
    }
    if (tid == 0) offs[n] = carry_s;  // == E
}

// ---- 3) counting-sort edges by target: srcs grouped per col ----
__global__ void bucket_kernel(const int* __restrict__ ei, int E,
                              int* __restrict__ cursor, int* __restrict__ srcs) {
    int e = blockIdx.x * blockDim.x + threadIdx.x;
    if (e < E) {
        int r = ei[e];          // source
        int c = ei[E + e];      // target
        int pos = atomicAdd(&cursor[c], 1);
        srcs[pos] = r;
    }
}

// ---- 4) z0 = dinv * x  (row-scale) ----
__global__ void scale_kernel(const float* __restrict__ x, const float* __restrict__ dinv,
                             float* __restrict__ z, int n) {
    int idx = blockIdx.x * blockDim.x + threadIdx.x;  // one float4 per thread
    int total = n * (D / 4);
    if (idx >= total) return;
    int node = idx / (D / 4);
    float4 v = ((const float4*)x)[idx];
    float s = dinv[node];
    v.x *= s; v.y *= s; v.z *= s; v.w *= s;
    ((float4*)z)[idx] = v;
}

// ---- 5) one hop: zout[c] = scale(c) * (zin[c] + sum_{in-nbrs r} zin[r])
//      mode 0: scale = dinv^2  (produces z1 from z0)
//      mode 1: scale = dinv    (produces x2 from z1)
__global__ __launch_bounds__(64) void prop_kernel(const float* __restrict__ zin,
                                                  float* __restrict__ zout,
                                                  const int* __restrict__ offs,
                                                  const int* __restrict__ srcs,
                                                  const float* __restrict__ dinv,
                                                  int mode) {
    int c = blockIdx.x;
    int lane = threadIdx.x;                       // 64 lanes x float2 = 128 dims
    const float2* zi = (const float2*)zin;
    float2 acc = zi[(size_t)c * (D / 2) + lane];  // self-loop term
    int beg = offs[c], end = offs[c + 1];
    for (int k = beg; k < end; ++k) {
        int r = srcs[k];
        float2 v = zi[(size_t)r * (D / 2) + lane];
        acc.x += v.x; acc.y += v.y;
    }
    float s = dinv[c];
    float scale = mode ? s : s * s;
    acc.x *= scale; acc.y *= scale;
    ((float2*)zout)[(size_t)c * (D / 2) + lane] = acc;
}

// ---- 6a) pre-transpose W (H x D) -> Wt (D x H) in global, once ----
__global__ void transpose_w(const float* __restrict__ W, float* __restrict__ Wt) {
    int j = blockIdx.x * blockDim.x + threadIdx.x;  // j = d*128 + h
    if (j < D * D) {
        int dd = j >> 7, h = j & 127;
        Wt[j] = W[h * D + dd];
    }
}

// ---- 6b) out = relu(x2 @ W^T + b), tile: 32 nodes x 128 h per block ----
__global__ __launch_bounds__(256) void gemm_kernel(const float* __restrict__ x2,
                                                   const float* __restrict__ Wt,
                                                   const float* __restrict__ b,
                                                   float* __restrict__ out, int n) {
    __shared__ float wt[D * D];    // 64 KB, wt[d*128 + h]
    __shared__ float xs[TN * D];   // 16 KB
    int t = threadIdx.x;
    for (int i = t; i < D * D; i += 256) wt[i] = Wt[i];          // coalesced, conflict-free
    int n0 = blockIdx.x * TN;
    for (int i = t; i < TN * D; i += 256) {
        int node = n0 + (i >> 7);
        xs[i] = (node < n) ? x2[(size_t)node * D + (i & 127)] : 0.f;
    }
    __syncthreads();

    int h0 = (t & 31) * 4;   // 4 consecutive h per thread
    int ni0 = t >> 5;        // node slots ni0, ni0+8, ni0+16, ni0+24
    float acc[4][4];
#pragma unroll
    for (int j = 0; j < 4; ++j) { acc[j][0] = acc[j][1] = acc[j][2] = acc[j][3] = 0.f; }

    for (int dd = 0; dd < D; ++dd) {
        float4 w4 = *(const float4*)(wt + dd * D + h0);   // canonical conflict-free float4
#pragma unroll
        for (int j = 0; j < 4; ++j) {
            float xv = xs[(ni0 + 8 * j) * D + dd];        // 2-way broadcast: free
            acc[j][0] += xv * w4.x;
            acc[j][1] += xv * w4.y;
            acc[j][2] += xv * w4.z;
            acc[j][3] += xv * w4.w;
        }
    }

    float4 bias = *(const float4*)(b + h0);
#pragma unroll
    for (int j = 0; j < 4; ++j) {
        int node = n0 + ni0 + 8 * j;
        if (node < n) {
            float4 o;
            o.x = fmaxf(acc[j][0] + bias.x, 0.f);
            o.y = fmaxf(acc[j][1] + bias.y, 0.f);
            o.z = fmaxf(acc[j][2] + bias.z, 0.f);
            o.w = fmaxf(acc[j][3] + bias.w, 0.f);
            *(float4*)(out + (size_t)node * D + h0) = o;  // coalesced 16B stores
        }
    }
}

extern "C" void kernel_launch(void* const* d_in, const int* in_sizes, int n_in,
                              void* d_out, int out_size, void* d_ws, size_t ws_size,
                              hipStream_t stream) {
    const float* x  = (const float*)d_in[0];
    const int*   ei = (const int*)d_in[1];
    const float* W  = (const float*)d_in[2];
    const float* b  = (const float*)d_in[3];
    float* out = (float*)d_out;
    int N = in_sizes[0] / D;   // 50000
    int E = in_sizes[1] / 2;   // 600000

    // workspace carve (512B aligned), ~54.5 MB total
    char* p = (char*)d_ws;
    auto alloc = [&](size_t bytes) -> void* {
        void* r = p; p += (bytes + 511) & ~(size_t)511; return r;
    };
    int*   deg    = (int*)alloc((size_t)N * 4);
    int*   offs   = (int*)alloc(((size_t)N + 1) * 4);
    int*   cursor = (int*)alloc((size_t)N * 4);
    int*   srcs   = (int*)alloc((size_t)E * 4);
    float* dinv   = (float*)alloc((size_t)N * 4);
    float* zA     = (float*)alloc((size_t)N * D * 4);
    float* zB     = (float*)alloc((size_t)N * D * 4);
    float* Wt     = (float*)alloc((size_t)D * D * 4);

    hipMemsetAsync(deg, 0, (size_t)N * 4, stream);  // ws is poisoned 0xAA each call
    count_kernel<<<(E + 255) / 256, 256, 0, stream>>>(ei, E, deg);
    scan_kernel<<<1, 1024, 0, stream>>>(deg, N, offs, cursor, dinv);
    bucket_kernel<<<(E + 255) / 256, 256, 0, stream>>>(ei, E, cursor, srcs);
    scale_kernel<<<(N * (D / 4) + 255) / 256, 256, 0, stream>>>(x, dinv, zA, N);
    transpose_w<<<(D * D + 255) / 256, 256, 0, stream>>>(W, Wt);
    prop_kernel<<<N, 64, 0, stream>>>(zA, zB, offs, srcs, dinv, 0);  // z1 = S^2 (A+I) z0
    prop_kernel<<<N, 64, 0, stream>>>(zB, zA, offs, srcs, dinv, 1);  // x2 = S   (A+I) z1
    gemm_kernel<<<(N + TN - 1) / TN, 256, 0, stream>>>(zA, Wt, b, out, N);
}

// Round 2
// 241.951 us; speedup vs baseline: 1.4986x; 1.4986x over previous
//
#include <hip/hip_runtime.h>

#define D 128
#define TN 32
typedef unsigned int uint;

// ---- bf16x2 pack/unpack (packed in a uint: low16 = even dim, high16 = odd dim) ----
__device__ __forceinline__ float2 bf2_to_f2(uint v) {
    union { uint u; float f; } a, b;
    a.u = v << 16;
    b.u = v & 0xffff0000u;
    return make_float2(a.f, b.f);
}
__device__ __forceinline__ uint f2_to_bf2(float x, float y) {
    uint xu = __float_as_uint(x), yu = __float_as_uint(y);
    xu += 0x7fffu + ((xu >> 16) & 1u);   // round-to-nearest-even
    yu += 0x7fffu + ((yu >> 16) & 1u);
    return (xu >> 16) | (yu & 0xffff0000u);
}

// ---- 1) count in-degree over targets (col = edge_index[1]) ----
__global__ void count_kernel(const int* __restrict__ ei, int E, int* __restrict__ deg) {
    int e = blockIdx.x * blockDim.x + threadIdx.x;
    if (e < E) atomicAdd(&deg[ei[E + e]], 1);
}

// ---- 2a) per-1024-chunk partial sums ----
__global__ __launch_bounds__(256) void scan_partial(const int* __restrict__ deg, int n,
                                                    int* __restrict__ partial) {
    __shared__ int red[256];
    int b = blockIdx.x, t = threadIdx.x;
    int base = b * 1024 + t * 4;
    int s = 0;
#pragma unroll
    for (int j = 0; j < 4; ++j) { int i = base + j; if (i < n) s += deg[i]; }
    red[t] = s;
    __syncthreads();
    for (int off = 128; off > 0; off >>= 1) {
        if (t < off) red[t] += red[t + off];
        __syncthreads();
    }
    if (t == 0) partial[b] = red[0];
}

// ---- 2b) exclusive scan of the (<=64) partials, one wave ----
__global__ __launch_bounds__(64) void scan_top(int* __restrict__ partial, int nb,
                                               int* __restrict__ offs, int n) {
    int t = threadIdx.x;
    int v = (t < nb) ? partial[t] : 0;
    int incl = v;
    for (int off = 1; off < 64; off <<= 1) {
        int o = __shfl_up(incl, off);
        if (t >= off) incl += o;
    }
    if (t < nb) partial[t] = incl - v;  // exclusive
    if (t == 63) offs[n] = incl;        // == E
}

// ---- 2c) local scan + apply: write offs/cursor/dinv ----
__global__ __launch_bounds__(256) void scan_apply(const int* __restrict__ deg, int n,
                                                  const int* __restrict__ partial,
                                                  int* __restrict__ offs, int* __restrict__ cursor,
                                                  float* __restrict__ dinv) {
    __shared__ int ts[256];
    int b = blockIdx.x, t = threadIdx.x;
    int base = b * 1024 + t * 4;
    int v[4]; int s = 0;
#pragma unroll
    for (int j = 0; j < 4; ++j) { int i = base + j; v[j] = (i < n) ? deg[i] : 0; s += v[j]; }
    ts[t] = s;
    __syncthreads();
    int val = s;
    for (int off = 1; off < 256; off <<= 1) {
        int add = (t >= off) ? ts[t - off] : 0;
        __syncthreads();
        val += add; ts[t] = val;
        __syncthreads();
    }
    int run = val - s + partial[b];  // exclusive offset of this thread's first element
#pragma unroll
    for (int j = 0; j < 4; ++j) {
        int i = base + j;
        if (i < n) {
            offs[i] = run; cursor[i] = run;
            dinv[i] = rsqrtf((float)(v[j] + 1));  // +1 self-loop
        }
        run += v[j];
    }
}

// ---- 3) counting-sort edges by target ----
__global__ void bucket_kernel(const int* __restrict__ ei, int E,
                              int* __restrict__ cursor, int* __restrict__ srcs) {
    int e = blockIdx.x * blockDim.x + threadIdx.x;
    if (e < E) {
        int r = ei[e];
        int c = ei[E + e];
        int pos = atomicAdd(&cursor[c], 1);
        srcs[pos] = r;
    }
}

// ---- 4) z0 = bf16(dinv * x) ----
__global__ void scale_kernel(const float* __restrict__ x, const float* __restrict__ dinv,
                             uint* __restrict__ z, int n) {
    int idx = blockIdx.x * blockDim.x + threadIdx.x;  // one bf16-pair per thread
    int total = n * (D / 2);
    if (idx >= total) return;
    int node = idx >> 6;
    float2 v = ((const float2*)x)[idx];
    float s = dinv[node];
    z[idx] = f2_to_bf2(v.x * s, v.y * s);
}

// ---- 5) one hop over bf16 rows (256 B/row), fp32 accumulate
//      mode 0: scale = dinv^2 ; mode 1: scale = dinv
__global__ __launch_bounds__(64) void prop_kernel(const uint* __restrict__ zin,
                                                  uint* __restrict__ zout,
                                                  const int* __restrict__ offs,
                                                  const int* __restrict__ srcs,
                                                  const float* __restrict__ dinv,
                                                  int mode) {
    int c = blockIdx.x;
    int lane = threadIdx.x;  // 64 lanes x bf16-pair = 128 dims
    size_t self = (size_t)c * 64 + lane;
    float2 acc = bf2_to_f2(zin[self]);  // self-loop term
    int beg = offs[c], end = offs[c + 1];
    int k = beg;
    for (; k + 3 < end; k += 4) {       // 4 rows in flight per wave
        int r0 = srcs[k], r1 = srcs[k + 1], r2 = srcs[k + 2], r3 = srcs[k + 3];
        uint v0 = zin[(size_t)r0 * 64 + lane];
        uint v1 = zin[(size_t)r1 * 64 + lane];
        uint v2 = zin[(size_t)r2 * 64 + lane];
        uint v3 = zin[(size_t)r3 * 64 + lane];
        float2 f0 = bf2_to_f2(v0), f1 = bf2_to_f2(v1), f2 = bf2_to_f2(v2), f3 = bf2_to_f2(v3);
        acc.x += (f0.x + f1.x) + (f2.x + f3.x);
        acc.y += (f0.y + f1.y) + (f2.y + f3.y);
    }
    for (; k < end; ++k) {
        float2 f = bf2_to_f2(zin[(size_t)srcs[k] * 64 + lane]);
        acc.x += f.x; acc.y += f.y;
    }
    float s = dinv[c];
    float scale = mode ? s : s * s;
    zout[self] = f2_to_bf2(acc.x * scale, acc.y * scale);
}

// ---- 6a) pre-transpose W (H x D) -> Wt (D x H) ----
__global__ void transpose_w(const float* __restrict__ W, float* __restrict__ Wt) {
    int j = blockIdx.x * blockDim.x + threadIdx.x;
    if (j < D * D) {
        int dd = j >> 7, h = j & 127;
        Wt[j] = W[h * D + dd];
    }
}

// ---- 6b) out = relu(x2 @ W^T + b); x2 is bf16-packed, fp32 accumulate ----
__global__ __launch_bounds__(256) void gemm_kernel(const uint* __restrict__ x2,
                                                   const float* __restrict__ Wt,
                                                   const float* __restrict__ b,
                                                   float* __restrict__ out, int n) {
    __shared__ float wt[D * D];    // 64 KB
    __shared__ float xs[TN * D];   // 16 KB
    int t = threadIdx.x;
    for (int i = t; i < D * D; i += 256) wt[i] = Wt[i];
    int n0 = blockIdx.x * TN;
    for (int i = t; i < TN * (D / 2); i += 256) {
        int node = n0 + (i >> 6);
        uint v = (node < n) ? x2[(size_t)node * 64 + (i & 63)] : 0u;
        float2 f = bf2_to_f2(v);
        int base = (i >> 6) * D + 2 * (i & 63);
        xs[base] = f.x; xs[base + 1] = f.y;
    }
    __syncthreads();

    int h0 = (t & 31) * 4;
    int ni0 = t >> 5;
    float acc[4][4];
#pragma unroll
    for (int j = 0; j < 4; ++j) { acc[j][0] = acc[j][1] = acc[j][2] = acc[j][3] = 0.f; }

    for (int dd = 0; dd < D; ++dd) {
        float4 w4 = *(const float4*)(wt + dd * D + h0);
#pragma unroll
        for (int j = 0; j < 4; ++j) {
            float xv = xs[(ni0 + 8 * j) * D + dd];
            acc[j][0] += xv * w4.x;
            acc[j][1] += xv * w4.y;
            acc[j][2] += xv * w4.z;
            acc[j][3] += xv * w4.w;
        }
    }

    float4 bias = *(const float4*)(b + h0);
#pragma unroll
    for (int j = 0; j < 4; ++j) {
        int node = n0 + ni0 + 8 * j;
        if (node < n) {
            float4 o;
            o.x = fmaxf(acc[j][0] + bias.x, 0.f);
            o.y = fmaxf(acc[j][1] + bias.y, 0.f);
            o.z = fmaxf(acc[j][2] + bias.z, 0.f);
            o.w = fmaxf(acc[j][3] + bias.w, 0.f);
            *(float4*)(out + (size_t)node * D + h0) = o;
        }
    }
}

extern "C" void kernel_launch(void* const* d_in, const int* in_sizes, int n_in,
                              void* d_out, int out_size, void* d_ws, size_t ws_size,
                              hipStream_t stream) {
    const float* x  = (const float*)d_in[0];
    const int*   ei = (const int*)d_in[1];
    const float* W  = (const float*)d_in[2];
    const float* b  = (const float*)d_in[3];
    float* out = (float*)d_out;
    int N = in_sizes[0] / D;   // 50000
    int E = in_sizes[1] / 2;   // 600000

    char* p = (char*)d_ws;
    auto alloc = [&](size_t bytes) -> void* {
        void* r = p; p += (bytes + 511) & ~(size_t)511; return r;
    };
    int*   deg     = (int*)alloc((size_t)N * 4);
    int*   offs    = (int*)alloc(((size_t)N + 1) * 4);
    int*   cursor  = (int*)alloc((size_t)N * 4);
    int*   srcs    = (int*)alloc((size_t)E * 4);
    float* dinv    = (float*)alloc((size_t)N * 4);
    int*   partial = (int*)alloc(64 * 4);
    uint*  zA      = (uint*)alloc((size_t)N * (D / 2) * 4);  // bf16-packed
    uint*  zB      = (uint*)alloc((size_t)N * (D / 2) * 4);
    float* Wt      = (float*)alloc((size_t)D * D * 4);

    int nb = (N + 1023) / 1024;  // 49 (must be <= 64 for scan_top)

    hipMemsetAsync(deg, 0, (size_t)N * 4, stream);
    count_kernel<<<(E + 255) / 256, 256, 0, stream>>>(ei, E, deg);
    scan_partial<<<nb, 256, 0, stream>>>(deg, N, partial);
    scan_top<<<1, 64, 0, stream>>>(partial, nb, offs, N);
    scan_apply<<<nb, 256, 0, stream>>>(deg, N, partial, offs, cursor, dinv);
    bucket_kernel<<<(E + 255) / 256, 256, 0, stream>>>(ei, E, cursor, srcs);
    scale_kernel<<<(N * (D / 2) + 255) / 256, 256, 0, stream>>>(x, dinv, zA, N);
    transpose_w<<<(D * D + 255) / 256, 256, 0, stream>>>(W, Wt);
    prop_kernel<<<N, 64, 0, stream>>>(zA, zB, offs, srcs, dinv, 0);  // z1 = S^2 (A+I) z0
    prop_kernel<<<N, 64, 0, stream>>>(zB, zA, offs, srcs, dinv, 1);  // x2 = S   (A+I) z1
    gemm_kernel<<<(N + TN - 1) / TN, 256, 0, stream>>>(zA, Wt, b, out, N);
}

// Round 3
// 240.059 us; speedup vs baseline: 1.5104x; 1.0079x over previous
//
#include <hip/hip_runtime.h>

#define D 128
typedef unsigned int uint;
typedef unsigned short ushort;
typedef __attribute__((ext_vector_type(8))) short bf16x8;
typedef __attribute__((ext_vector_type(4))) float f32x4;

// ---- bf16x2 pack/unpack (packed uint: low16 = even dim, high16 = odd dim) ----
__device__ __forceinline__ float2 bf2_to_f2(uint v) {
    union { uint u; float f; } a, b;
    a.u = v << 16;
    b.u = v & 0xffff0000u;
    return make_float2(a.f, b.f);
}
__device__ __forceinline__ uint f2_to_bf2(float x, float y) {
    uint xu = __float_as_uint(x), yu = __float_as_uint(y);
    xu += 0x7fffu + ((xu >> 16) & 1u);   // round-to-nearest-even
    yu += 0x7fffu + ((yu >> 16) & 1u);
    return (xu >> 16) | (yu & 0xffff0000u);
}

// ---- 1) count in-degree over targets ----
__global__ void count_kernel(const int* __restrict__ ei, int E, int* __restrict__ deg) {
    int e = blockIdx.x * blockDim.x + threadIdx.x;
    if (e < E) atomicAdd(&deg[ei[E + e]], 1);
}

// ---- 2a) per-1024-chunk partial sums ----
__global__ __launch_bounds__(256) void scan_partial(const int* __restrict__ deg, int n,
                                                    int* __restrict__ partial) {
    __shared__ int red[256];
    int b = blockIdx.x, t = threadIdx.x;
    int base = b * 1024 + t * 4;
    int s = 0;
#pragma unroll
    for (int j = 0; j < 4; ++j) { int i = base + j; if (i < n) s += deg[i]; }
    red[t] = s;
    __syncthreads();
    for (int off = 128; off > 0; off >>= 1) {
        if (t < off) red[t] += red[t + off];
        __syncthreads();
    }
    if (t == 0) partial[b] = red[0];
}

// ---- 2b) exclusive scan of (<=64) partials, one wave ----
__global__ __launch_bounds__(64) void scan_top(int* __restrict__ partial, int nb,
                                               int* __restrict__ offs, int n) {
    int t = threadIdx.x;
    int v = (t < nb) ? partial[t] : 0;
    int incl = v;
    for (int off = 1; off < 64; off <<= 1) {
        int o = __shfl_up(incl, off);
        if (t >= off) incl += o;
    }
    if (t < nb) partial[t] = incl - v;
    if (t == 63) offs[n] = incl;  // == E
}

// ---- 2c) local scan + apply ----
__global__ __launch_bounds__(256) void scan_apply(const int* __restrict__ deg, int n,
                                                  const int* __restrict__ partial,
                                                  int* __restrict__ offs, int* __restrict__ cursor,
                                                  float* __restrict__ dinv) {
    __shared__ int ts[256];
    int b = blockIdx.x, t = threadIdx.x;
    int base = b * 1024 + t * 4;
    int v[4]; int s = 0;
#pragma unroll
    for (int j = 0; j < 4; ++j) { int i = base + j; v[j] = (i < n) ? deg[i] : 0; s += v[j]; }
    ts[t] = s;
    __syncthreads();
    int val = s;
    for (int off = 1; off < 256; off <<= 1) {
        int add = (t >= off) ? ts[t - off] : 0;
        __syncthreads();
        val += add; ts[t] = val;
        __syncthreads();
    }
    int run = val - s + partial[b];
#pragma unroll
    for (int j = 0; j < 4; ++j) {
        int i = base + j;
        if (i < n) {
            offs[i] = run; cursor[i] = run;
            dinv[i] = rsqrtf((float)(v[j] + 1));
        }
        run += v[j];
    }
}

// ---- 3) counting-sort edges by target ----
__global__ void bucket_kernel(const int* __restrict__ ei, int E,
                              int* __restrict__ cursor, int* __restrict__ srcs) {
    int e = blockIdx.x * blockDim.x + threadIdx.x;
    if (e < E) {
        int r = ei[e];
        int c = ei[E + e];
        int pos = atomicAdd(&cursor[c], 1);
        srcs[pos] = r;
    }
}

// ---- 4) z0 = bf16(dinv * x) ----
__global__ void scale_kernel(const float* __restrict__ x, const float* __restrict__ dinv,
                             uint* __restrict__ z, int n) {
    int idx = blockIdx.x * blockDim.x + threadIdx.x;
    int total = n * (D / 2);
    if (idx >= total) return;
    int node = idx >> 6;
    float2 v = ((const float2*)x)[idx];
    float s = dinv[node];
    z[idx] = f2_to_bf2(v.x * s, v.y * s);
}

// ---- 4b) W fp32 -> bf16, native H x D layout (no transpose: MFMA B-frag wants W rows) ----
__global__ void wcast_kernel(const float* __restrict__ W, ushort* __restrict__ Wbf) {
    int i = blockIdx.x * 256 + threadIdx.x;
    if (i < D * D) {
        uint u = __float_as_uint(W[i]);
        u += 0x7fffu + ((u >> 16) & 1u);
        Wbf[i] = (ushort)(u >> 16);
    }
}

// ---- 5) one hop: 4 waves/block, 1 node/wave, half-wave per row (uint2 = 8B/lane)
//      mode 0: scale = dinv^2 ; mode 1: scale = dinv
__global__ __launch_bounds__(256) void prop_kernel(const uint2* __restrict__ zin,
                                                   uint2* __restrict__ zout,
                                                   const int* __restrict__ offs,
                                                   const int* __restrict__ srcs,
                                                   const float* __restrict__ dinv,
                                                   int mode, int n) {
    int w = threadIdx.x >> 6, lane = threadIdx.x & 63;
    int c = blockIdx.x * 4 + w;
    if (c >= n) return;
    int half = lane >> 5, l32 = lane & 31;  // lane covers dims 4*l32 .. 4*l32+3

    float4 acc = make_float4(0.f, 0.f, 0.f, 0.f);
    if (half == 0) {  // self-loop term, added once
        uint2 sv = zin[(size_t)c * 32 + l32];
        float2 lo = bf2_to_f2(sv.x), hi = bf2_to_f2(sv.y);
        acc = make_float4(lo.x, lo.y, hi.x, hi.y);
    }
    int beg = offs[c], end = offs[c + 1];
    int k = beg + half;          // half 0: even slots, half 1: odd slots
    for (; k + 2 < end; k += 4) {  // 2 rows per half -> 4 rows in flight per wave
        int r0 = srcs[k], r1 = srcs[k + 2];
        uint2 v0 = zin[(size_t)r0 * 32 + l32];
        uint2 v1 = zin[(size_t)r1 * 32 + l32];
        float2 a0 = bf2_to_f2(v0.x), b0 = bf2_to_f2(v0.y);
        float2 a1 = bf2_to_f2(v1.x), b1 = bf2_to_f2(v1.y);
        acc.x += a0.x + a1.x; acc.y += a0.y + a1.y;
        acc.z += b0.x + b1.x; acc.w += b0.y + b1.y;
    }
    for (; k < end; k += 2) {
        uint2 v0 = zin[(size_t)srcs[k] * 32 + l32];
        float2 a0 = bf2_to_f2(v0.x), b0 = bf2_to_f2(v0.y);
        acc.x += a0.x; acc.y += a0.y; acc.z += b0.x; acc.w += b0.y;
    }
    // fold half 1 into half 0
    acc.x += __shfl_xor(acc.x, 32);
    acc.y += __shfl_xor(acc.y, 32);
    acc.z += __shfl_xor(acc.z, 32);
    acc.w += __shfl_xor(acc.w, 32);
    if (half == 0) {
        float s = dinv[c];
        float scale = mode ? s : s * s;
        uint2 o;
        o.x = f2_to_bf2(acc.x * scale, acc.y * scale);
        o.y = f2_to_bf2(acc.z * scale, acc.w * scale);
        zout[(size_t)c * 32 + l32] = o;
    }
}

// ---- 6) out = relu(x2 @ W^T + b) via MFMA bf16; 64 nodes/block, 16 nodes/wave ----
#define GN 64
__global__ __launch_bounds__(256) void gemm_mfma(const uint4* __restrict__ x2,
                                                 const uint4* __restrict__ Wbf,
                                                 const float* __restrict__ bias,
                                                 float* __restrict__ out, int n) {
    __shared__ __align__(16) ushort xs[GN][136];   // +8 pad: even 8-lane/bank b128 reads
    __shared__ __align__(16) ushort ws[D][136];
    int t = threadIdx.x;
    int n0 = blockIdx.x * GN;
    for (int i = t; i < D * 16; i += 256) {        // W: 2048 x 16B
        int row = i >> 4, c8 = i & 15;
        uint4 v = Wbf[i];
        *(uint4*)&ws[row][c8 * 8] = v;
    }
    for (int i = t; i < GN * 16; i += 256) {       // x2 tile: 1024 x 16B
        int row = i >> 4, c8 = i & 15;
        int node = n0 + row;
        uint4 v = (node < n) ? x2[(size_t)node * 16 + c8] : make_uint4(0u, 0u, 0u, 0u);
        *(uint4*)&xs[row][c8 * 8] = v;
    }
    __syncthreads();

    int w = t >> 6, lane = t & 63;
    int m0 = w * 16;                 // wave's 16-node slice
    int mrow = lane & 15, quad = lane >> 4;

    // A frag: A[m=lane&15][k=q*32+quad*8+j]  (verified layout)
    bf16x8 a[4];
#pragma unroll
    for (int q = 0; q < 4; ++q)
        a[q] = *(const bf16x8*)&xs[m0 + mrow][q * 32 + quad * 8];

    f32x4 acc[8];
#pragma unroll
    for (int ht = 0; ht < 8; ++ht) {
        acc[ht] = (f32x4){0.f, 0.f, 0.f, 0.f};
#pragma unroll
        for (int q = 0; q < 4; ++q) {
            // B frag: B[k=q*32+quad*8+j][n=lane&15] = W[h=n][d=k] -> native W rows
            bf16x8 bfr = *(const bf16x8*)&ws[ht * 16 + mrow][q * 32 + quad * 8];
            acc[ht] = __builtin_amdgcn_mfma_f32_16x16x32_bf16(a[q], bfr, acc[ht], 0, 0, 0);
        }
    }

    // C/D: col = lane&15 (h), row = quad*4+reg (node-within-tile)
#pragma unroll
    for (int ht = 0; ht < 8; ++ht) {
        int h = ht * 16 + mrow;
        float bv = bias[h];
#pragma unroll
        for (int reg = 0; reg < 4; ++reg) {
            int node = n0 + m0 + quad * 4 + reg;
            if (node < n)
                out[(size_t)node * D + h] = fmaxf(acc[ht][reg] + bv, 0.f);
        }
    }
}

extern "C" void kernel_launch(void* const* d_in, const int* in_sizes, int n_in,
                              void* d_out, int out_size, void* d_ws, size_t ws_size,
                              hipStream_t stream) {
    const float* x  = (const float*)d_in[0];
    const int*   ei = (const int*)d_in[1];
    const float* W  = (const float*)d_in[2];
    const float* b  = (const float*)d_in[3];
    float* out = (float*)d_out;
    int N = in_sizes[0] / D;   // 50000
    int E = in_sizes[1] / 2;   // 600000

    char* p = (char*)d_ws;
    auto alloc = [&](size_t bytes) -> void* {
        void* r = p; p += (bytes + 511) & ~(size_t)511; return r;
    };
    int*    deg     = (int*)alloc((size_t)N * 4);
    int*    offs    = (int*)alloc(((size_t)N + 1) * 4);
    int*    cursor  = (int*)alloc((size_t)N * 4);
    int*    srcs    = (int*)alloc((size_t)E * 4);
    float*  dinv    = (float*)alloc((size_t)N * 4);
    int*    partial = (int*)alloc(64 * 4);
    uint*   zA      = (uint*)alloc((size_t)N * (D / 2) * 4);  // bf16-packed
    uint*   zB      = (uint*)alloc((size_t)N * (D / 2) * 4);
    ushort* Wbf     = (ushort*)alloc((size_t)D * D * 2);

    int nb = (N + 1023) / 1024;  // 49

    hipMemsetAsync(deg, 0, (size_t)N * 4, stream);
    count_kernel<<<(E + 255) / 256, 256, 0, stream>>>(ei, E, deg);
    scan_partial<<<nb, 256, 0, stream>>>(deg, N, partial);
    scan_top<<<1, 64, 0, stream>>>(partial, nb, offs, N);
    scan_apply<<<nb, 256, 0, stream>>>(deg, N, partial, offs, cursor, dinv);
    bucket_kernel<<<(E + 255) / 256, 256, 0, stream>>>(ei, E, cursor, srcs);
    scale_kernel<<<(N * (D / 2) + 255) / 256, 256, 0, stream>>>(x, dinv, zA, N);
    wcast_kernel<<<(D * D + 255) / 256, 256, 0, stream>>>(W, Wbf);
    prop_kernel<<<(N + 3) / 4, 256, 0, stream>>>((const uint2*)zA, (uint2*)zB, offs, srcs, dinv, 0, N);
    prop_kernel<<<(N + 3) / 4, 256, 0, stream>>>((const uint2*)zB, (uint2*)zA, offs, srcs, dinv, 1, N);
    gemm_mfma<<<(N + GN - 1) / GN, 256, 0, stream>>>((const uint4*)zA, (const uint4*)Wbf, b, out, N);
}

// Round 4
// 235.847 us; speedup vs baseline: 1.5374x; 1.0179x over previous
//
#include <hip/hip_runtime.h>

#define D 128
typedef unsigned int uint;
typedef unsigned short ushort;
typedef __attribute__((ext_vector_type(8))) short bf16x8;
typedef __attribute__((ext_vector_type(4))) float f32x4;

// ---- bf16x2 pack/unpack (packed uint: low16 = even dim, high16 = odd dim) ----
__device__ __forceinline__ float2 bf2_to_f2(uint v) {
    union { uint u; float f; } a, b;
    a.u = v << 16;
    b.u = v & 0xffff0000u;
    return make_float2(a.f, b.f);
}
__device__ __forceinline__ uint f2_to_bf2(float x, float y) {
    uint xu = __float_as_uint(x), yu = __float_as_uint(y);
    xu += 0x7fffu + ((xu >> 16) & 1u);   // round-to-nearest-even
    yu += 0x7fffu + ((yu >> 16) & 1u);
    return (xu >> 16) | (yu & 0xffff0000u);
}

// ---- 1) count in-degree into per-XCD private copies (j = blockIdx&7 ~ XCD id) ----
// 4 edges per thread via int4. Grid shape MUST match bucket_kernel exactly.
__global__ __launch_bounds__(256) void count_kernel(const int* __restrict__ ei, int E,
                                                    int* __restrict__ deg8, int N) {
    int j = blockIdx.x & 7;
    int* d = deg8 + j * N;
    int base = (blockIdx.x * 256 + threadIdx.x) * 4;
    if (base + 3 < E) {
        int4 t = *(const int4*)(ei + E + base);
        atomicAdd(&d[t.x], 1); atomicAdd(&d[t.y], 1);
        atomicAdd(&d[t.z], 1); atomicAdd(&d[t.w], 1);
    } else {
        for (int e = base; e < E; ++e) atomicAdd(&d[ei[E + e]], 1);
    }
}

// ---- 2a) per-1024-node partial sums over the 8 copies ----
__global__ __launch_bounds__(256) void scan_partial(const int* __restrict__ deg8, int n, int N,
                                                    int* __restrict__ partial) {
    __shared__ int red[256];
    int b = blockIdx.x, t = threadIdx.x;
    int base = b * 1024 + t * 4;
    int s = 0;
#pragma unroll
    for (int jj = 0; jj < 4; ++jj) {
        int i = base + jj;
        if (i < n) {
#pragma unroll
            for (int j = 0; j < 8; ++j) s += deg8[j * N + i];
        }
    }
    red[t] = s;
    __syncthreads();
    for (int off = 128; off > 0; off >>= 1) {
        if (t < off) red[t] += red[t + off];
        __syncthreads();
    }
    if (t == 0) partial[b] = red[0];
}

// ---- 2b) exclusive scan of (<=64) partials, one wave ----
__global__ __launch_bounds__(64) void scan_top(int* __restrict__ partial, int nb,
                                               int* __restrict__ offs, int n) {
    int t = threadIdx.x;
    int v = (t < nb) ? partial[t] : 0;
    int incl = v;
    for (int off = 1; off < 64; off <<= 1) {
        int o = __shfl_up(incl, off);
        if (t >= off) incl += o;
    }
    if (t < nb) partial[t] = incl - v;
    if (t == 63) offs[n] = incl;  // == E
}

// ---- 2c) local scan + apply: offs, dinv, and 8 per-XCD cursor sub-ranges ----
__global__ __launch_bounds__(256) void scan_apply(const int* __restrict__ deg8, int n, int N,
                                                  const int* __restrict__ partial,
                                                  int* __restrict__ offs, int* __restrict__ cursorc,
                                                  float* __restrict__ dinv) {
    __shared__ int ts[256];
    int b = blockIdx.x, t = threadIdx.x;
    int base = b * 1024 + t * 4;
    int d[4][8], tot[4]; int s = 0;
#pragma unroll
    for (int jj = 0; jj < 4; ++jj) {
        int i = base + jj;
        tot[jj] = 0;
#pragma unroll
        for (int j = 0; j < 8; ++j) {
            d[jj][j] = (i < n) ? deg8[j * N + i] : 0;
            tot[jj] += d[jj][j];
        }
        s += tot[jj];
    }
    ts[t] = s;
    __syncthreads();
    int val = s;
    for (int off = 1; off < 256; off <<= 1) {
        int add = (t >= off) ? ts[t - off] : 0;
        __syncthreads();
        val += add; ts[t] = val;
        __syncthreads();
    }
    int run = val - s + partial[b];
#pragma unroll
    for (int jj = 0; jj < 4; ++jj) {
        int i = base + jj;
        if (i < n) {
            offs[i] = run;
            dinv[i] = rsqrtf((float)(tot[jj] + 1));  // +1 self-loop
            int sub = run;
#pragma unroll
            for (int j = 0; j < 8; ++j) { cursorc[j * N + i] = sub; sub += d[jj][j]; }
        }
        run += tot[jj];
    }
}

// ---- 3) counting-sort edges by target, XCD-local cursors (grid == count grid) ----
__global__ __launch_bounds__(256) void bucket_kernel(const int* __restrict__ ei, int E,
                                                     int* __restrict__ cursorc,
                                                     int* __restrict__ srcs, int N) {
    int j = blockIdx.x & 7;
    int* cur = cursorc + j * N;
    int base = (blockIdx.x * 256 + threadIdx.x) * 4;
    if (base + 3 < E) {
        int4 r = *(const int4*)(ei + base);
        int4 c = *(const int4*)(ei + E + base);
        srcs[atomicAdd(&cur[c.x], 1)] = r.x;
        srcs[atomicAdd(&cur[c.y], 1)] = r.y;
        srcs[atomicAdd(&cur[c.z], 1)] = r.z;
        srcs[atomicAdd(&cur[c.w], 1)] = r.w;
    } else {
        for (int e = base; e < E; ++e)
            srcs[atomicAdd(&cur[ei[E + e]], 1)] = ei[e];
    }
}

// ---- 4) fused: z0 = bf16(dinv * x)  +  W fp32->bf16 cast (tail blocks) ----
__global__ void scale_kernel(const float* __restrict__ x, const float* __restrict__ dinv,
                             uint* __restrict__ z, int n, int nScaleBlocks,
                             const float* __restrict__ W, ushort* __restrict__ Wbf) {
    if (blockIdx.x < (uint)nScaleBlocks) {
        int idx = blockIdx.x * 256 + threadIdx.x;
        int total = n * (D / 2);
        if (idx >= total) return;
        int node = idx >> 6;
        float2 v = ((const float2*)x)[idx];
        float s = dinv[node];
        z[idx] = f2_to_bf2(v.x * s, v.y * s);
    } else {
        int i = (blockIdx.x - nScaleBlocks) * 256 + threadIdx.x;
        if (i < D * D) {
            uint u = __float_as_uint(W[i]);
            u += 0x7fffu + ((u >> 16) & 1u);
            Wbf[i] = (ushort)(u >> 16);
        }
    }
}

// ---- 5) one hop: 4 waves/block, 1 node/wave, half-wave per row (uint2 = 8B/lane),
//      contiguous sublist per half, 4 rows in flight per half (8 per wave)
//      mode 0: scale = dinv^2 ; mode 1: scale = dinv
__global__ __launch_bounds__(256) void prop_kernel(const uint2* __restrict__ zin,
                                                   uint2* __restrict__ zout,
                                                   const int* __restrict__ offs,
                                                   const int* __restrict__ srcs,
                                                   const float* __restrict__ dinv,
                                                   int mode, int n) {
    int w = threadIdx.x >> 6, lane = threadIdx.x & 63;
    int c = blockIdx.x * 4 + w;
    if (c >= n) return;
    int half = lane >> 5, l32 = lane & 31;

    float4 acc = make_float4(0.f, 0.f, 0.f, 0.f);
    if (half == 0) {  // self-loop term, added once
        uint2 sv = zin[(size_t)c * 32 + l32];
        float2 lo = bf2_to_f2(sv.x), hi = bf2_to_f2(sv.y);
        acc = make_float4(lo.x, lo.y, hi.x, hi.y);
    }
    int beg = offs[c], end = offs[c + 1];
    int len = end - beg;
    int L1 = (len + 1) >> 1;
    int k = beg + (half ? L1 : 0);
    int e = half ? end : beg + L1;
    for (; k + 3 < e; k += 4) {   // 4 rows in flight per half
        int r0 = srcs[k], r1 = srcs[k + 1], r2 = srcs[k + 2], r3 = srcs[k + 3];
        uint2 v0 = zin[(size_t)r0 * 32 + l32];
        uint2 v1 = zin[(size_t)r1 * 32 + l32];
        uint2 v2 = zin[(size_t)r2 * 32 + l32];
        uint2 v3 = zin[(size_t)r3 * 32 + l32];
        float2 a0 = bf2_to_f2(v0.x), b0 = bf2_to_f2(v0.y);
        float2 a1 = bf2_to_f2(v1.x), b1 = bf2_to_f2(v1.y);
        float2 a2 = bf2_to_f2(v2.x), b2 = bf2_to_f2(v2.y);
        float2 a3 = bf2_to_f2(v3.x), b3 = bf2_to_f2(v3.y);
        acc.x += (a0.x + a1.x) + (a2.x + a3.x);
        acc.y += (a0.y + a1.y) + (a2.y + a3.y);
        acc.z += (b0.x + b1.x) + (b2.x + b3.x);
        acc.w += (b0.y + b1.y) + (b2.y + b3.y);
    }
    for (; k < e; ++k) {
        uint2 v0 = zin[(size_t)srcs[k] * 32 + l32];
        float2 a0 = bf2_to_f2(v0.x), b0 = bf2_to_f2(v0.y);
        acc.x += a0.x; acc.y += a0.y; acc.z += b0.x; acc.w += b0.y;
    }
    acc.x += __shfl_xor(acc.x, 32);
    acc.y += __shfl_xor(acc.y, 32);
    acc.z += __shfl_xor(acc.z, 32);
    acc.w += __shfl_xor(acc.w, 32);
    if (half == 0) {
        float s = dinv[c];
        float scale = mode ? s : s * s;
        uint2 o;
        o.x = f2_to_bf2(acc.x * scale, acc.y * scale);
        o.y = f2_to_bf2(acc.z * scale, acc.w * scale);
        zout[(size_t)c * 32 + l32] = o;
    }
}

// ---- 6) out = relu(x2 @ W^T + b) via MFMA bf16; 64 nodes/block, 16 nodes/wave ----
#define GN 64
__global__ __launch_bounds__(256) void gemm_mfma(const uint4* __restrict__ x2,
                                                 const uint4* __restrict__ Wbf,
                                                 const float* __restrict__ bias,
                                                 float* __restrict__ out, int n) {
    __shared__ __align__(16) ushort xs[GN][136];   // +8 pad: even 8-lane/bank b128 reads
    __shared__ __align__(16) ushort ws[D][136];
    int t = threadIdx.x;
    int n0 = blockIdx.x * GN;
    for (int i = t; i < D * 16; i += 256) {
        int row = i >> 4, c8 = i & 15;
        uint4 v = Wbf[i];
        *(uint4*)&ws[row][c8 * 8] = v;
    }
    for (int i = t; i < GN * 16; i += 256) {
        int row = i >> 4, c8 = i & 15;
        int node = n0 + row;
        uint4 v = (node < n) ? x2[(size_t)node * 16 + c8] : make_uint4(0u, 0u, 0u, 0u);
        *(uint4*)&xs[row][c8 * 8] = v;
    }
    __syncthreads();

    int w = t >> 6, lane = t & 63;
    int m0 = w * 16;
    int mrow = lane & 15, quad = lane >> 4;

    bf16x8 a[4];
#pragma unroll
    for (int q = 0; q < 4; ++q)
        a[q] = *(const bf16x8*)&xs[m0 + mrow][q * 32 + quad * 8];

    f32x4 acc[8];
#pragma unroll
    for (int ht = 0; ht < 8; ++ht) {
        acc[ht] = (f32x4){0.f, 0.f, 0.f, 0.f};
#pragma unroll
        for (int q = 0; q < 4; ++q) {
            bf16x8 bfr = *(const bf16x8*)&ws[ht * 16 + mrow][q * 32 + quad * 8];
            acc[ht] = __builtin_amdgcn_mfma_f32_16x16x32_bf16(a[q], bfr, acc[ht], 0, 0, 0);
        }
    }

#pragma unroll
    for (int ht = 0; ht < 8; ++ht) {
        int h = ht * 16 + mrow;
        float bv = bias[h];
#pragma unroll
        for (int reg = 0; reg < 4; ++reg) {
            int node = n0 + m0 + quad * 4 + reg;
            if (node < n)
                out[(size_t)node * D + h] = fmaxf(acc[ht][reg] + bv, 0.f);
        }
    }
}

extern "C" void kernel_launch(void* const* d_in, const int* in_sizes, int n_in,
                              void* d_out, int out_size, void* d_ws, size_t ws_size,
                              hipStream_t stream) {
    const float* x  = (const float*)d_in[0];
    const int*   ei = (const int*)d_in[1];
    const float* W  = (const float*)d_in[2];
    const float* b  = (const float*)d_in[3];
    float* out = (float*)d_out;
    int N = in_sizes[0] / D;   // 50000
    int E = in_sizes[1] / 2;   // 600000

    char* p = (char*)d_ws;
    auto alloc = [&](size_t bytes) -> void* {
        void* r = p; p += (bytes + 511) & ~(size_t)511; return r;
    };
    int*    deg8    = (int*)alloc((size_t)8 * N * 4);   // per-XCD copies
    int*    offs    = (int*)alloc(((size_t)N + 1) * 4);
    int*    cursorc = (int*)alloc((size_t)8 * N * 4);   // per-XCD cursors
    int*    srcs    = (int*)alloc((size_t)E * 4);
    float*  dinv    = (float*)alloc((size_t)N * 4);
    int*    partial = (int*)alloc(64 * 4);
    uint*   zA      = (uint*)alloc((size_t)N * (D / 2) * 4);  // bf16-packed
    uint*   zB      = (uint*)alloc((size_t)N * (D / 2) * 4);
    ushort* Wbf     = (ushort*)alloc((size_t)D * D * 2);

    int nb = (N + 1023) / 1024;                 // 49
    int ebBlocks = (E + 1023) / 1024;           // 586, same grid for count & bucket
    int nScaleBlocks = (N * (D / 2) + 255) / 256;
    int nWBlocks = (D * D + 255) / 256;

    hipMemsetAsync(deg8, 0, (size_t)8 * N * 4, stream);
    count_kernel<<<ebBlocks, 256, 0, stream>>>(ei, E, deg8, N);
    scan_partial<<<nb, 256, 0, stream>>>(deg8, N, N, partial);
    scan_top<<<1, 64, 0, stream>>>(partial, nb, offs, N);
    scan_apply<<<nb, 256, 0, stream>>>(deg8, N, N, partial, offs, cursorc, dinv);
    bucket_kernel<<<ebBlocks, 256, 0, stream>>>(ei, E, cursorc, srcs, N);
    scale_kernel<<<nScaleBlocks + nWBlocks, 256, 0, stream>>>(x, dinv, zA, N, nScaleBlocks, W, Wbf);
    prop_kernel<<<(N + 3) / 4, 256, 0, stream>>>((const uint2*)zA, (uint2*)zB, offs, srcs, dinv, 0, N);
    prop_kernel<<<(N + 3) / 4, 256, 0, stream>>>((const uint2*)zB, (uint2*)zA, offs, srcs, dinv, 1, N);
    gemm_mfma<<<(N + GN - 1) / GN, 256, 0, stream>>>((const uint4*)zA, (const uint4*)Wbf, b, out, N);
}